// Round 2
// baseline (382.507 us; speedup 1.0000x reference)
//
#include <hip/hip_runtime.h>

// int4 weight-only quantized GEMV: out[n] = sum_k A[k] * W[n,k]
//   W[n,k] = (nib(B)[n,k] - 8) * scale[n, k/32] + zero[n, k/32]
// M=1, K=8192, N=16384, GROUP=32.
// Dtypes (confirmed R2-R4): A [8192] f32, B [N, K/2] int32 (1 byte payload,
// low nibble = even k), SZ [N, 256, 2] f32, out [N] f32.
//
// R9 theory: prior 512-thread/ROWS=8 shape ran 16 waves/CU and sustained only
// ~33 HBM lines in flight/CU (2.9 TB/s). RMSNorm-class streaming kernels on
// this chip hold 57+ lines/CU (4.9-5.2 TB/s) at 8 waves/SIMD -> the cap was
// occupancy/structure, not TCP MSHRs. This version: 256 threads, ROWS=2,
// <=64 VGPR (launch_bounds(256,8)) -> 32 waves/CU; A re-read per pass from
// L1/L2 (32 KB, hot) instead of 16 regs; SZ direct nt loads (no LDS stage,
// no pre-stream barrier); all 8 B nt loads issued upfront, monotone drain.
// R10: compile fix — nontemporal builtin needs ext_vector_type, not float2.

#define ROWS   2
#define TPB    256
#define PASSES 4          // 1024 ivec4 per row / 256 threads

typedef int   ivec4 __attribute__((ext_vector_type(4)));
typedef float fvec2 __attribute__((ext_vector_type(2)));

__global__ __launch_bounds__(TPB, 8) void gemv_w4hi(
    const float4* __restrict__ A4,   // 8192 f32 = 2048 float4
    const ivec4*  __restrict__ B,    // [N, 1024] int4x4 (16B = 4 int32 = 8 k)
    const fvec2*  __restrict__ SZ,   // [N, 256] (scale, zero) f32 pairs
    float* __restrict__ out,         // [N] f32
    int N)
{
    const int t  = threadIdx.x;
    const int n0 = blockIdx.x * ROWS;

    // ---- issue ALL B loads upfront, non-temporal (streaming, no-allocate) ---
    const ivec4* B0 = B + (size_t)n0 * 1024 + t;
    ivec4 b[PASSES][ROWS];
#pragma unroll
    for (int p = 0; p < PASSES; ++p)
#pragma unroll
        for (int r = 0; r < ROWS; ++r)
            b[p][r] = __builtin_nontemporal_load(&B0[(size_t)r * 1024 + p * 256]);

    float acc[ROWS];
#pragma unroll
    for (int r = 0; r < ROWS; ++r) acc[r] = 0.0f;

    // ---- consume in issue order (monotone vmcnt drain) ----
#pragma unroll
    for (int p = 0; p < PASSES; ++p) {
        const int i = t + 256 * p;            // ivec4 index; k = 8i..8i+7
        // A slice: 32 B from global -- A is 32 KB total, L1/L2-resident.
        const float4 x = A4[2 * i];
        const float4 y = A4[2 * i + 1];
        const float a0 = x.x, a1 = x.y, a2 = x.z, a3 = x.w;
        const float a4 = y.x, a5 = y.y, a6 = y.z, a7 = y.w;
        const float sA = ((a0 + a1) + (a2 + a3)) + ((a4 + a5) + (a6 + a7));
        const int g = i >> 2;                 // quant group (32 k = 4 ivec4)
#pragma unroll
        for (int r = 0; r < ROWS; ++r) {
            const fvec2 sz =
                __builtin_nontemporal_load(&SZ[(size_t)(n0 + r) * 256 + g]);
            const int b0 = b[p][r][0], b1 = b[p][r][1];
            const int b2 = b[p][r][2], b3 = b[p][r][3];
            float dot = 0.0f;
            dot = fmaf(a0, (float)(b0 & 0xF),        dot);
            dot = fmaf(a1, (float)((b0 >> 4) & 0xF), dot);
            dot = fmaf(a2, (float)(b1 & 0xF),        dot);
            dot = fmaf(a3, (float)((b1 >> 4) & 0xF), dot);
            dot = fmaf(a4, (float)(b2 & 0xF),        dot);
            dot = fmaf(a5, (float)((b2 >> 4) & 0xF), dot);
            dot = fmaf(a6, (float)(b3 & 0xF),        dot);
            dot = fmaf(a7, (float)((b3 >> 4) & 0xF), dot);
            const float s  = sz[0];
            const float zz = fmaf(-8.0f, s, sz[1]);  // z - 8s
            acc[r] = fmaf(s,  dot, acc[r]);
            acc[r] = fmaf(zz, sA,  acc[r]);
        }
    }

    // ---- reduce: wave shuffle per row, LDS across 4 waves ----
    __shared__ float red[ROWS][TPB / 64];
    const int lane = t & 63;
    const int w    = t >> 6;
#pragma unroll
    for (int r = 0; r < ROWS; ++r) {
        float v = acc[r];
#pragma unroll
        for (int off = 32; off > 0; off >>= 1)
            v += __shfl_down(v, off, 64);
        if (lane == 0) red[r][w] = v;
    }
    __syncthreads();
    if (t < ROWS) {
        const int n = n0 + t;
        if (n < N) {
            float v = 0.0f;
#pragma unroll
            for (int w2 = 0; w2 < TPB / 64; ++w2) v += red[t][w2];
            out[n] = v;
        }
    }
}

extern "C" void kernel_launch(void* const* d_in, const int* in_sizes, int n_in,
                              void* d_out, int out_size, void* d_ws, size_t ws_size,
                              hipStream_t stream) {
    const float4* A4 = (const float4*)d_in[0];   // f32[8192]
    const ivec4*  B  = (const ivec4*)d_in[1];    // int32[N, 4096]
    const fvec2*  SZ = (const fvec2*)d_in[2];    // f32[N, 256, 2]
    float* out = (float*)d_out;                  // f32[N]

    const int N = out_size;                      // 16384
    gemv_w4hi<<<N / ROWS, TPB, 0, stream>>>(A4, B, SZ, out, N);
}

// Round 3
// 351.537 us; speedup vs baseline: 1.0881x; 1.0881x over previous
//
#include <hip/hip_runtime.h>

// int4 weight-only quantized GEMV: out[n] = sum_k A[k] * W[n,k]
//   W[n,k] = (nib(B)[n,k] - 8) * scale[n, k/32] + zero[n, k/32]
// M=1, K=8192, N=16384, GROUP=32.
// Dtypes: A [8192] f32, B [N, K/2] int32 (1 byte payload, low nibble = even k),
// SZ [N, 256, 2] f32, out [N] f32.
//
// R11: CONTINUITY, not occupancy. R10 (2x occupancy, loads in consume loop)
// regressed -> occupancy falsified. R5-R8 were all one-shot-per-block: each
// block's prologue (SZ stage + barrier) and epilogue have ZERO B loads in
// flight -> time-avg in-flight ~4 KB/CU = 2.9 TB/s (need only ~10 KB for
// 6.3 TB/s). This version: persistent block owning 32 rows = 16 tiles of 2,
// software-pipelined: issue tile T+1's burst before consuming tile T
// (double-buffered B regs, double-buffered SZ LDS + red LDS; the alternating
// barrier makes depth-2 race-free). Consume mapping is R8's verbatim.
// VGPR ~75 < 128 cap (512,4); grid 512 = exactly 2 blocks/CU, zero tail.

#define TPB   512
#define ROWS  2
#define TILES 16
#define CROWS (ROWS * TILES)   // 32 rows per block

typedef int   ivec4 __attribute__((ext_vector_type(4)));
typedef float fvec2 __attribute__((ext_vector_type(2)));

__global__ __launch_bounds__(TPB, 4) void gemv_w4pipe(
    const float4* __restrict__ A4,   // 8192 f32 = 2048 float4
    const ivec4*  __restrict__ B,    // [N, 1024] (16B = 4 int32 = 8 k)
    const fvec2*  __restrict__ SZ,   // [N, 256] (scale, zero) f32 pairs
    float* __restrict__ out,         // [N] f32
    int N)
{
    const int t    = threadIdx.x;
    const int row0 = blockIdx.x * CROWS;
    const int g0   = t >> 2;

    __shared__ fvec2 sz_s[2][ROWS * 256];      // 2 x 4 KB
    __shared__ float red[2][ROWS][TPB / 64];   // 2 x 2 x 8

    // ---- A -> regs ONCE per block (thread t covers ivec4 t and t+512) ----
    float a[2][8];
    float sA[2];
#pragma unroll
    for (int j = 0; j < 2; ++j) {
        const int i = t + 512 * j;
        const float4 x = A4[2 * i];
        const float4 y = A4[2 * i + 1];
        a[j][0] = x.x; a[j][1] = x.y; a[j][2] = x.z; a[j][3] = x.w;
        a[j][4] = y.x; a[j][5] = y.y; a[j][6] = y.z; a[j][7] = y.w;
        sA[j] = ((x.x + x.y) + (x.z + x.w)) + ((y.x + y.y) + (y.z + y.w));
    }

    ivec4 bufA[ROWS][2], bufB[ROWS][2];
    fvec2 szrA, szrB;

    // issue tile T's loads (1 SZ fvec2 + 4 B ivec4 per thread), non-temporal
    auto issue = [&](int T, ivec4 (&buf)[ROWS][2], fvec2& szr) {
        const int rt = row0 + T * ROWS;
        szr = __builtin_nontemporal_load(&SZ[(size_t)rt * 256 + t]);
        const ivec4* Bp = B + (size_t)rt * 1024 + t;
#pragma unroll
        for (int r = 0; r < ROWS; ++r)
#pragma unroll
            for (int j = 0; j < 2; ++j)
                buf[r][j] = __builtin_nontemporal_load(&Bp[r * 1024 + 512 * j]);
    };

    // consume a tile from regs + LDS-resident SZ; leave row partials in redb
    auto consume = [&](const ivec4 (&buf)[ROWS][2], const fvec2* szl,
                       float (&redb)[ROWS][TPB / 64]) {
        float acc[ROWS];
#pragma unroll
        for (int r = 0; r < ROWS; ++r) acc[r] = 0.0f;
#pragma unroll
        for (int r = 0; r < ROWS; ++r) {
#pragma unroll
            for (int j = 0; j < 2; ++j) {
                const fvec2 sz = szl[r * 256 + g0 + 128 * j];
                const int b0 = buf[r][j][0], b1 = buf[r][j][1];
                const int b2 = buf[r][j][2], b3 = buf[r][j][3];
                float dot = 0.0f;
                dot = fmaf(a[j][0], (float)(b0 & 0xF),        dot);
                dot = fmaf(a[j][1], (float)((b0 >> 4) & 0xF), dot);
                dot = fmaf(a[j][2], (float)(b1 & 0xF),        dot);
                dot = fmaf(a[j][3], (float)((b1 >> 4) & 0xF), dot);
                dot = fmaf(a[j][4], (float)(b2 & 0xF),        dot);
                dot = fmaf(a[j][5], (float)((b2 >> 4) & 0xF), dot);
                dot = fmaf(a[j][6], (float)(b3 & 0xF),        dot);
                dot = fmaf(a[j][7], (float)((b3 >> 4) & 0xF), dot);
                acc[r] = fmaf(sz[0], dot, acc[r]);
                acc[r] = fmaf(fmaf(-8.0f, sz[0], sz[1]), sA[j], acc[r]);
            }
        }
        const int lane = t & 63;
        const int w    = t >> 6;
#pragma unroll
        for (int r = 0; r < ROWS; ++r) {
            float v = acc[r];
#pragma unroll
            for (int off = 32; off > 0; off >>= 1)
                v += __shfl_down(v, off, 64);
            if (lane == 0) redb[r][w] = v;
        }
    };

    auto store2 = [&](int T, const float (&redb)[ROWS][TPB / 64]) {
        if (t < ROWS) {
            const int n = row0 + T * ROWS + t;
            if (n < N) {
                float v = 0.0f;
#pragma unroll
                for (int w2 = 0; w2 < TPB / 64; ++w2) v += redb[t][w2];
                out[n] = v;
            }
        }
    };

    // ---- prologue: tile 0 in flight, SZ0 staged ----
    issue(0, bufA, szrA);
    sz_s[0][t] = szrA;
    __syncthreads();

    // ---- pipelined main loop: 2 tiles per iteration, all indices static ----
    for (int TT = 0; TT < TILES; TT += 2) {
        // tile TT (buffers A, parity 0)
        if (TT + 1 < TILES) issue(TT + 1, bufB, szrB);
        consume(bufA, &sz_s[0][0], red[0]);
        if (TT + 1 < TILES) sz_s[1][t] = szrB;
        __syncthreads();
        store2(TT, red[0]);

        // tile TT+1 (buffers B, parity 1)
        if (TT + 2 < TILES) issue(TT + 2, bufA, szrA);
        consume(bufB, &sz_s[1][0], red[1]);
        if (TT + 2 < TILES) sz_s[0][t] = szrA;
        __syncthreads();
        store2(TT + 1, red[1]);
    }
}

extern "C" void kernel_launch(void* const* d_in, const int* in_sizes, int n_in,
                              void* d_out, int out_size, void* d_ws, size_t ws_size,
                              hipStream_t stream) {
    const float4* A4 = (const float4*)d_in[0];   // f32[8192]
    const ivec4*  B  = (const ivec4*)d_in[1];    // int32[N, 4096]
    const fvec2*  SZ = (const fvec2*)d_in[2];    // f32[N, 256, 2]
    float* out = (float*)d_out;                  // f32[N]

    const int N = out_size;                      // 16384
    gemv_w4pipe<<<N / CROWS, TPB, 0, stream>>>(A4, B, SZ, out, N);
}